// Round 4
// baseline (369.778 us; speedup 1.0000x reference)
//
#include <hip/hip_runtime.h>

#define M_DIM 8192
#define N_DIM 6144
#define K_DIM 3072
#define NKT 96            // K / 32 K-tiles
#define NBK (K_DIM / 128) // 24 scale blocks along K

typedef __attribute__((ext_vector_type(8))) short short8;
typedef __attribute__((ext_vector_type(4))) float f32x4v;

// round-to-nearest-even f32->bf16, two packed into a u32
__device__ __forceinline__ unsigned int pk2bf(float a, float b) {
  unsigned int ua = __float_as_uint(a);
  unsigned int ub = __float_as_uint(b);
  ua = (ua + 0x7FFFu + ((ua >> 16) & 1u)) >> 16;
  ub = (ub + 0x7FFFu + ((ub >> 16) & 1u)) & 0xFFFF0000u;
  return ua | ub;
}

__global__ void cvt_x(const float* __restrict__ X, uint2* __restrict__ O, int n4) {
  int stride = gridDim.x * blockDim.x;
  for (int i = blockIdx.x * blockDim.x + threadIdx.x; i < n4; i += stride) {
    float4 v = ((const float4*)X)[i];
    O[i] = make_uint2(pk2bf(v.x, v.y), pk2bf(v.z, v.w));
  }
}

__global__ void cvt_w(const float* __restrict__ W, const float* __restrict__ S,
                      uint2* __restrict__ O, int n4) {
  int stride = gridDim.x * blockDim.x;
  for (int i = blockIdx.x * blockDim.x + threadIdx.x; i < n4; i += stride) {
    unsigned int e = (unsigned int)i * 4u;
    unsigned int n = e / K_DIM;
    unsigned int k = e - n * K_DIM;
    float s = S[(n >> 7) * NBK + (k >> 7)];
    float4 v = ((const float4*)W)[i];
    O[i] = make_uint2(pk2bf(v.x * s, v.y * s), pk2bf(v.z * s, v.w * s));
  }
}

__device__ __forceinline__ void gload16(const unsigned short* g, unsigned short* l) {
  __builtin_amdgcn_global_load_lds(
      (const __attribute__((address_space(1))) void*)g,
      (__attribute__((address_space(3))) void*)l, 16, 0, 0);
}

// 256x256 tile, BK=32, ring-4 LDS slots, counted vmcnt(8) crossing raw barriers.
// LDS subtile layout is chunk-major: each (16-row x 32-k) subtile stored as
// [q][r][16B], so a fragment read is lds_base + lane*16 (contiguous, 0-conflict).
// Staging pre-permutes the per-lane GLOBAL source to match (LDS dest stays linear).
__global__ __launch_bounds__(512, 2) void gemm_ring(
    const unsigned short* __restrict__ Xb, const unsigned short* __restrict__ Wb,
    float* __restrict__ Y) {
  extern __shared__ unsigned short lds[];   // As[4][8192] ++ Bs[4][8192] = 128 KB
  unsigned short* As = lds;
  unsigned short* Bs = lds + 32768;

  // XCD-aware mapping: 768 blocks = 8 XCD x 96; each XCD owns 4 bm-panels x 24 bn
  int bid = blockIdx.x;
  int c = bid & 7;
  int j = bid >> 3;                 // 0..95
  int bm = c * 4 + (j / 24);        // 0..31
  int bn = j % 24;                  // 0..23

  int tid = threadIdx.x;
  int lane = tid & 63;
  int wr = (tid >> 6) >> 2;         // 0..1  (wave M row)
  int wc = (tid >> 6) & 3;          // 0..3  (wave N col)

  // staging source permutation: thread t feeds LDS byte t*16 of the 8KB half,
  // which is subtile (t>>6), k-chunk (t>>4)&3, row (t&15) in chunk-major layout
  int g_row = ((tid >> 6) << 4) + (tid & 15);   // 0..127 (+128 on 2nd instr)
  int g_kc  = (tid >> 4) & 3;                   // k-chunk (8 bf16 = 16B)
  const unsigned short* Xg = Xb + ((size_t)bm * 256 + g_row) * K_DIM + g_kc * 8;
  const unsigned short* Wg = Wb + ((size_t)bn * 256 + g_row) * K_DIM + g_kc * 8;
  unsigned short* lax = As + tid * 8;       // linear LDS dest (uniform + lane*16B)
  unsigned short* lbx = Bs + tid * 8;

  // fragment read bases: contiguous per wave (lane*16B within 1KB subtile)
  const unsigned short* Ab = As + wr * 4096 + lane * 8;   // subtiles wr*8 .. wr*8+7
  const unsigned short* Bb = Bs + wc * 2048 + lane * 8;   // subtiles wc*4 .. wc*4+3

#define STAGE(t) { int _sl = ((t) & 3) * 8192;                                  \
    const unsigned short* _xp = Xg + (size_t)(t) * 32;                          \
    const unsigned short* _wp = Wg + (size_t)(t) * 32;                          \
    gload16(_xp, lax + _sl);                                                    \
    gload16(_xp + (size_t)128 * K_DIM, lax + _sl + 4096);                       \
    gload16(_wp, lbx + _sl);                                                    \
    gload16(_wp + (size_t)128 * K_DIM, lbx + _sl + 4096); }

  f32x4v acc[8][4];
#pragma unroll
  for (int m = 0; m < 8; ++m)
#pragma unroll
    for (int n = 0; n < 4; ++n) acc[m][n] = (f32x4v)0.0f;

  STAGE(0); STAGE(1); STAGE(2);   // 12 loads in flight

  // BODY(t): wait own tile-t loads (counted), barrier (all waves' loads landed;
  // slot (t+3)&3 = (t-1)&3 free since iter t-1 reads done before this barrier),
  // issue stage t+3, ds_read 12 frags from slot t&3, 32 MFMA under setprio.
#define BODY(t, VM, DOSTAGE) {                                                  \
    asm volatile("s_waitcnt vmcnt(" #VM ")\n\ts_barrier" ::: "memory");         \
    if (DOSTAGE) STAGE((t) + 3);                                                \
    int sl = ((t) & 3) * 8192;                                                  \
    short8 a[8], b[4];                                                          \
    _Pragma("unroll") for (int n = 0; n < 4; ++n)                               \
      b[n] = *(const short8*)(Bb + sl + n * 512);                               \
    _Pragma("unroll") for (int m = 0; m < 8; ++m)                               \
      a[m] = *(const short8*)(Ab + sl + m * 512);                               \
    __builtin_amdgcn_s_setprio(1);                                              \
    _Pragma("unroll") for (int m = 0; m < 8; ++m)                               \
      _Pragma("unroll") for (int n = 0; n < 4; ++n)                             \
        acc[m][n] = __builtin_amdgcn_mfma_f32_16x16x32_bf16(a[m], b[n], acc[m][n], 0, 0, 0); \
    __builtin_amdgcn_s_setprio(0); }

  for (int tt = 0; tt < NKT - 4; tt += 4) {   // t = 0..91, stages 3..94
    BODY(tt + 0, 8, 1);
    BODY(tt + 1, 8, 1);
    BODY(tt + 2, 8, 1);
    BODY(tt + 3, 8, 1);
  }
  BODY(92, 8, 1);   // stages 95
  BODY(93, 8, 0);
  BODY(94, 4, 0);
  BODY(95, 0, 0);
#undef BODY
#undef STAGE

  // C/D layout: ncol = lane&15, mrow = (lane>>4)*4 + reg
  int mrow0 = bm * 256 + wr * 128 + ((lane >> 4) << 2);
  int ncol0 = bn * 256 + wc * 64 + (lane & 15);
#pragma unroll
  for (int m = 0; m < 8; ++m)
#pragma unroll
    for (int n = 0; n < 4; ++n)
#pragma unroll
      for (int r = 0; r < 4; ++r)
        Y[(size_t)(mrow0 + m * 16 + r) * N_DIM + ncol0 + n * 16] = acc[m][n][r];
}

// ================= fallback (R1 kernel) if ws too small =================
#define BM 128
#define BN 128
#define NTN (N_DIM / BN)
#define NK2 (K_DIM / 64)
__global__ __launch_bounds__(256, 2) void dq_gemm(
    const float* __restrict__ X, const float* __restrict__ W,
    const float* __restrict__ S, float* __restrict__ Y) {
  __shared__ unsigned short As[BM * 64];
  __shared__ unsigned short Bs[BN * 64];
  int bid = blockIdx.x;
  int cpx = gridDim.x >> 3;
  int wg = (bid & 7) * cpx + (bid >> 3);
  int bm = wg / NTN, bn = wg - (wg / NTN) * NTN;
  int tid = threadIdx.x, lane = tid & 63, wave = tid >> 6;
  int wm = (wave >> 1) << 6, wn = (wave & 1) << 6;
  const float* Xg = X + (size_t)bm * BM * K_DIM;
  const float* Wg = W + (size_t)bn * BN * K_DIM;
  int r0 = tid >> 4, c4 = tid & 15;
  f32x4v acc[4][4];
#pragma unroll
  for (int i = 0; i < 4; ++i)
#pragma unroll
    for (int jj = 0; jj < 4; ++jj) acc[i][jj] = (f32x4v)0.0f;
  float4 xa[8], xb[8];
#pragma unroll
  for (int i = 0; i < 8; ++i) xa[i] = *(const float4*)(Xg + (size_t)(i * 16 + r0) * K_DIM + c4 * 4);
#pragma unroll
  for (int i = 0; i < 8; ++i) xb[i] = *(const float4*)(Wg + (size_t)(i * 16 + r0) * K_DIM + c4 * 4);
  char* Ac = (char*)As; char* Bc = (char*)Bs;
  int sw = (lane & 7) << 4, kb = (lane >> 4) << 4;
  int rA = wm + (lane & 15), rB = wn + (lane & 15);
  for (int kk = 0; kk < NK2; ++kk) {
    float s = S[bn * NBK + (kk >> 1)];
    __syncthreads();
#pragma unroll
    for (int i = 0; i < 8; ++i) {
      int row = i * 16 + r0;
      int off = row * 128 + ((c4 * 8) ^ ((row & 7) << 4));
      *(uint2*)(Ac + off) = make_uint2(pk2bf(xa[i].x, xa[i].y), pk2bf(xa[i].z, xa[i].w));
      *(uint2*)(Bc + off) = make_uint2(pk2bf(xb[i].x * s, xb[i].y * s), pk2bf(xb[i].z * s, xb[i].w * s));
    }
    __syncthreads();
    if (kk + 1 < NK2) {
      const float* Xn = Xg + (size_t)(kk + 1) * 64;
      const float* Wn = Wg + (size_t)(kk + 1) * 64;
#pragma unroll
      for (int i = 0; i < 8; ++i) xa[i] = *(const float4*)(Xn + (size_t)(i * 16 + r0) * K_DIM + c4 * 4);
#pragma unroll
      for (int i = 0; i < 8; ++i) xb[i] = *(const float4*)(Wn + (size_t)(i * 16 + r0) * K_DIM + c4 * 4);
    }
    short8 a0[4], a1[4], b0[4], b1[4];
#pragma unroll
    for (int i = 0; i < 4; ++i) {
      int rowA = rA + i * 16, rowB = rB + i * 16;
      a0[i] = *(const short8*)(Ac + rowA * 128 + (kb ^ sw));
      a1[i] = *(const short8*)(Ac + rowA * 128 + ((kb + 64) ^ sw));
      b0[i] = *(const short8*)(Bc + rowB * 128 + (kb ^ sw));
      b1[i] = *(const short8*)(Bc + rowB * 128 + ((kb + 64) ^ sw));
    }
#pragma unroll
    for (int i = 0; i < 4; ++i)
#pragma unroll
      for (int jj = 0; jj < 4; ++jj) {
        acc[i][jj] = __builtin_amdgcn_mfma_f32_16x16x32_bf16(a0[i], b0[jj], acc[i][jj], 0, 0, 0);
        acc[i][jj] = __builtin_amdgcn_mfma_f32_16x16x32_bf16(a1[i], b1[jj], acc[i][jj], 0, 0, 0);
      }
  }
  int mrow0 = bm * BM + wm + ((lane >> 4) << 2);
  int ncol0 = bn * BN + wn + (lane & 15);
#pragma unroll
  for (int i = 0; i < 4; ++i)
#pragma unroll
    for (int jj = 0; jj < 4; ++jj)
#pragma unroll
      for (int r = 0; r < 4; ++r)
        Y[(size_t)(mrow0 + i * 16 + r) * N_DIM + ncol0 + jj * 16] = acc[i][jj][r];
}

extern "C" void kernel_launch(void* const* d_in, const int* in_sizes, int n_in,
                              void* d_out, int out_size, void* d_ws, size_t ws_size,
                              hipStream_t stream) {
  const float* X = (const float*)d_in[0];
  const float* W = (const float*)d_in[1];
  const float* S = (const float*)d_in[2];
  float* Y = (float*)d_out;

  const size_t xb_bytes = (size_t)M_DIM * K_DIM * 2;
  const size_t wb_bytes = (size_t)N_DIM * K_DIM * 2;
  if (ws_size >= xb_bytes + wb_bytes) {
    unsigned short* Xbf = (unsigned short*)d_ws;
    unsigned short* Wbf = (unsigned short*)((char*)d_ws + xb_bytes);
    cvt_x<<<2048, 256, 0, stream>>>(X, (uint2*)Xbf, M_DIM * K_DIM / 4);
    cvt_w<<<2048, 256, 0, stream>>>(W, S, (uint2*)Wbf, N_DIM * K_DIM / 4);
    static int attr_set = 0;
    if (!attr_set) {
      hipFuncSetAttribute((const void*)gemm_ring,
                          hipFuncAttributeMaxDynamicSharedMemorySize, 131072);
      attr_set = 1;
    }
    dim3 grid((M_DIM / 256) * (N_DIM / 256));  // 32 * 24 = 768
    gemm_ring<<<grid, 512, 131072, stream>>>(Xbf, Wbf, Y);
  } else {
    dim3 grid((M_DIM / BM) * (N_DIM / BN));
    dq_gemm<<<grid, 256, 0, stream>>>(X, W, S, Y);
  }
}

// Round 5
// 328.093 us; speedup vs baseline: 1.1271x; 1.1271x over previous
//
#include <hip/hip_runtime.h>

#define M_DIM 8192
#define N_DIM 6144
#define K_DIM 3072
#define NKT 96            // K / 32 K-tiles
#define NBK (K_DIM / 128) // 24 scale blocks along K

typedef __attribute__((ext_vector_type(8))) short short8;
typedef __attribute__((ext_vector_type(4))) float f32x4v;

// round-to-nearest-even f32->bf16, two packed into a u32
__device__ __forceinline__ unsigned int pk2bf(float a, float b) {
  unsigned int ua = __float_as_uint(a);
  unsigned int ub = __float_as_uint(b);
  ua = (ua + 0x7FFFu + ((ua >> 16) & 1u)) >> 16;
  ub = (ub + 0x7FFFu + ((ub >> 16) & 1u)) & 0xFFFF0000u;
  return ua | ub;
}

__global__ void cvt_x(const float* __restrict__ X, uint2* __restrict__ O, int n4) {
  int stride = gridDim.x * blockDim.x;
  for (int i = blockIdx.x * blockDim.x + threadIdx.x; i < n4; i += stride) {
    float4 v = ((const float4*)X)[i];
    O[i] = make_uint2(pk2bf(v.x, v.y), pk2bf(v.z, v.w));
  }
}

__global__ void cvt_w(const float* __restrict__ W, const float* __restrict__ S,
                      uint2* __restrict__ O, int n4) {
  int stride = gridDim.x * blockDim.x;
  for (int i = blockIdx.x * blockDim.x + threadIdx.x; i < n4; i += stride) {
    unsigned int e = (unsigned int)i * 4u;
    unsigned int n = e / K_DIM;
    unsigned int k = e - n * K_DIM;
    float s = S[(n >> 7) * NBK + (k >> 7)];
    float4 v = ((const float4*)W)[i];
    O[i] = make_uint2(pk2bf(v.x * s, v.y * s), pk2bf(v.z * s, v.w * s));
  }
}

__device__ __forceinline__ void gload16(const unsigned short* g, unsigned short* l) {
  __builtin_amdgcn_global_load_lds(
      (const __attribute__((address_space(1))) void*)g,
      (__attribute__((address_space(3))) void*)l, 16, 0, 0);
}

// 256x256 tile, BK=32, ring-4 LDS slots, counted vmcnt(8) crossing raw barriers.
// LDS layout: row-major 64B rows (as R3), with quad-local XOR swizzle
//   chunk q stored at q ^ ((row>>1)&3) — permutes 16B chunks WITHIN each 64B row.
// Staging keeps R3's coalesced order (4 lanes cover one contiguous 64B line;
// source chunk pre-permuted inside the line). Fragment reads apply the same XOR
// -> every 16-lane group lands 2 lanes/bank-quad (free, m136).
__global__ __launch_bounds__(512, 2) void gemm_ring(
    const unsigned short* __restrict__ Xb, const unsigned short* __restrict__ Wb,
    float* __restrict__ Y) {
  extern __shared__ unsigned short lds[];   // As[4][8192] ++ Bs[4][8192] = 128 KB
  unsigned short* As = lds;
  unsigned short* Bs = lds + 32768;

  // XCD-aware mapping: 768 blocks = 8 XCD x 96; each XCD owns 4 bm-panels x 24 bn
  int bid = blockIdx.x;
  int c = bid & 7;
  int j = bid >> 3;                 // 0..95
  int bm = c * 4 + (j / 24);        // 0..31
  int bn = j % 24;                  // 0..23

  int tid = threadIdx.x;
  int lane = tid & 63;
  int wr = (tid >> 6) >> 2;         // 0..1  (wave M row)
  int wc = (tid >> 6) & 3;          // 0..3  (wave N col)

  // staging: thread t covers rows (t>>2)+{0,128}, 16B chunk ((t&3) ^ ((t>>3)&3))
  // of the row's 64B K-slice (quad-local permutation of a contiguous line)
  int s_row = tid >> 2;                        // 0..127
  int s_q   = (tid & 3) ^ ((tid >> 3) & 3);    // swizzled source chunk
  const unsigned short* Xg = Xb + ((size_t)bm * 256 + s_row) * K_DIM + s_q * 8;
  const unsigned short* Wg = Wb + ((size_t)bn * 256 + s_row) * K_DIM + s_q * 8;
  unsigned short* lax = As + tid * 8;       // linear LDS dest (uniform + lane*16B)
  unsigned short* lbx = Bs + tid * 8;

  // fragment read bases: row r = lane&15 (+16 per frag), chunk (lane>>4)^((lane>>1)&3)
  int fr = lane & 15;
  int fq = (lane >> 4) ^ ((lane >> 1) & 3);
  const unsigned short* Ab = As + ((wr * 128 + fr) << 5) + (fq << 3);
  const unsigned short* Bb = Bs + ((wc * 64 + fr) << 5) + (fq << 3);

#define STAGE(t) { int _sl = ((t) & 3) * 8192;                                  \
    const unsigned short* _xp = Xg + (size_t)(t) * 32;                          \
    const unsigned short* _wp = Wg + (size_t)(t) * 32;                          \
    gload16(_xp, lax + _sl);                                                    \
    gload16(_xp + (size_t)128 * K_DIM, lax + _sl + 4096);                       \
    gload16(_wp, lbx + _sl);                                                    \
    gload16(_wp + (size_t)128 * K_DIM, lbx + _sl + 4096); }

  f32x4v acc[8][4];
#pragma unroll
  for (int m = 0; m < 8; ++m)
#pragma unroll
    for (int n = 0; n < 4; ++n) acc[m][n] = (f32x4v)0.0f;

  STAGE(0); STAGE(1); STAGE(2);   // 12 loads in flight

  // BODY(t): wait own tile-t loads (counted), barrier (all waves' loads landed;
  // slot (t+3)&3 free: iter t-1 reads completed before each wave reached here),
  // issue stage t+3, ds_read 12 frags from slot t&3, 32 MFMA under setprio.
#define BODY(t, VM, DOSTAGE) {                                                  \
    asm volatile("s_waitcnt vmcnt(" #VM ")\n\ts_barrier" ::: "memory");         \
    if (DOSTAGE) STAGE((t) + 3);                                                \
    int sl = ((t) & 3) * 8192;                                                  \
    short8 a[8], b[4];                                                          \
    _Pragma("unroll") for (int n = 0; n < 4; ++n)                               \
      b[n] = *(const short8*)(Bb + sl + n * 512);                               \
    _Pragma("unroll") for (int m = 0; m < 8; ++m)                               \
      a[m] = *(const short8*)(Ab + sl + m * 512);                               \
    __builtin_amdgcn_s_setprio(1);                                              \
    _Pragma("unroll") for (int m = 0; m < 8; ++m)                               \
      _Pragma("unroll") for (int n = 0; n < 4; ++n)                             \
        acc[m][n] = __builtin_amdgcn_mfma_f32_16x16x32_bf16(a[m], b[n], acc[m][n], 0, 0, 0); \
    __builtin_amdgcn_s_setprio(0); }

  for (int tt = 0; tt < NKT - 4; tt += 4) {   // t = 0..91, stages 3..94
    BODY(tt + 0, 8, 1);
    BODY(tt + 1, 8, 1);
    BODY(tt + 2, 8, 1);
    BODY(tt + 3, 8, 1);
  }
  BODY(92, 8, 1);   // stages 95
  BODY(93, 8, 0);
  BODY(94, 4, 0);
  BODY(95, 0, 0);
#undef BODY
#undef STAGE

  // C/D layout: ncol = lane&15, mrow = (lane>>4)*4 + reg
  int mrow0 = bm * 256 + wr * 128 + ((lane >> 4) << 2);
  int ncol0 = bn * 256 + wc * 64 + (lane & 15);
#pragma unroll
  for (int m = 0; m < 8; ++m)
#pragma unroll
    for (int n = 0; n < 4; ++n)
#pragma unroll
      for (int r = 0; r < 4; ++r)
        Y[(size_t)(mrow0 + m * 16 + r) * N_DIM + ncol0 + n * 16] = acc[m][n][r];
}

// ================= fallback (R1 kernel) if ws too small =================
#define BM 128
#define BN 128
#define NTN (N_DIM / BN)
#define NK2 (K_DIM / 64)
__global__ __launch_bounds__(256, 2) void dq_gemm(
    const float* __restrict__ X, const float* __restrict__ W,
    const float* __restrict__ S, float* __restrict__ Y) {
  __shared__ unsigned short As[BM * 64];
  __shared__ unsigned short Bs[BN * 64];
  int bid = blockIdx.x;
  int cpx = gridDim.x >> 3;
  int wg = (bid & 7) * cpx + (bid >> 3);
  int bm = wg / NTN, bn = wg - (wg / NTN) * NTN;
  int tid = threadIdx.x, lane = tid & 63, wave = tid >> 6;
  int wm = (wave >> 1) << 6, wn = (wave & 1) << 6;
  const float* Xg = X + (size_t)bm * BM * K_DIM;
  const float* Wg = W + (size_t)bn * BN * K_DIM;
  int r0 = tid >> 4, c4 = tid & 15;
  f32x4v acc[4][4];
#pragma unroll
  for (int i = 0; i < 4; ++i)
#pragma unroll
    for (int jj = 0; jj < 4; ++jj) acc[i][jj] = (f32x4v)0.0f;
  float4 xa[8], xb[8];
#pragma unroll
  for (int i = 0; i < 8; ++i) xa[i] = *(const float4*)(Xg + (size_t)(i * 16 + r0) * K_DIM + c4 * 4);
#pragma unroll
  for (int i = 0; i < 8; ++i) xb[i] = *(const float4*)(Wg + (size_t)(i * 16 + r0) * K_DIM + c4 * 4);
  char* Ac = (char*)As; char* Bc = (char*)Bs;
  int sw = (lane & 7) << 4, kb = (lane >> 4) << 4;
  int rA = wm + (lane & 15), rB = wn + (lane & 15);
  for (int kk = 0; kk < NK2; ++kk) {
    float s = S[bn * NBK + (kk >> 1)];
    __syncthreads();
#pragma unroll
    for (int i = 0; i < 8; ++i) {
      int row = i * 16 + r0;
      int off = row * 128 + ((c4 * 8) ^ ((row & 7) << 4));
      *(uint2*)(Ac + off) = make_uint2(pk2bf(xa[i].x, xa[i].y), pk2bf(xa[i].z, xa[i].w));
      *(uint2*)(Bc + off) = make_uint2(pk2bf(xb[i].x * s, xb[i].y * s), pk2bf(xb[i].z * s, xb[i].w * s));
    }
    __syncthreads();
    if (kk + 1 < NK2) {
      const float* Xn = Xg + (size_t)(kk + 1) * 64;
      const float* Wn = Wg + (size_t)(kk + 1) * 64;
#pragma unroll
      for (int i = 0; i < 8; ++i) xa[i] = *(const float4*)(Xn + (size_t)(i * 16 + r0) * K_DIM + c4 * 4);
#pragma unroll
      for (int i = 0; i < 8; ++i) xb[i] = *(const float4*)(Wn + (size_t)(i * 16 + r0) * K_DIM + c4 * 4);
    }
    short8 a0[4], a1[4], b0[4], b1[4];
#pragma unroll
    for (int i = 0; i < 4; ++i) {
      int rowA = rA + i * 16, rowB = rB + i * 16;
      a0[i] = *(const short8*)(Ac + rowA * 128 + (kb ^ sw));
      a1[i] = *(const short8*)(Ac + rowA * 128 + ((kb + 64) ^ sw));
      b0[i] = *(const short8*)(Bc + rowB * 128 + (kb ^ sw));
      b1[i] = *(const short8*)(Bc + rowB * 128 + ((kb + 64) ^ sw));
    }
#pragma unroll
    for (int i = 0; i < 4; ++i)
#pragma unroll
      for (int jj = 0; jj < 4; ++jj) {
        acc[i][jj] = __builtin_amdgcn_mfma_f32_16x16x32_bf16(a0[i], b0[jj], acc[i][jj], 0, 0, 0);
        acc[i][jj] = __builtin_amdgcn_mfma_f32_16x16x32_bf16(a1[i], b1[jj], acc[i][jj], 0, 0, 0);
      }
  }
  int mrow0 = bm * BM + wm + ((lane >> 4) << 2);
  int ncol0 = bn * BN + wn + (lane & 15);
#pragma unroll
  for (int i = 0; i < 4; ++i)
#pragma unroll
    for (int jj = 0; jj < 4; ++jj)
#pragma unroll
      for (int r = 0; r < 4; ++r)
        Y[(size_t)(mrow0 + i * 16 + r) * N_DIM + ncol0 + jj * 16] = acc[i][jj][r];
}

extern "C" void kernel_launch(void* const* d_in, const int* in_sizes, int n_in,
                              void* d_out, int out_size, void* d_ws, size_t ws_size,
                              hipStream_t stream) {
  const float* X = (const float*)d_in[0];
  const float* W = (const float*)d_in[1];
  const float* S = (const float*)d_in[2];
  float* Y = (float*)d_out;

  const size_t xb_bytes = (size_t)M_DIM * K_DIM * 2;
  const size_t wb_bytes = (size_t)N_DIM * K_DIM * 2;
  if (ws_size >= xb_bytes + wb_bytes) {
    unsigned short* Xbf = (unsigned short*)d_ws;
    unsigned short* Wbf = (unsigned short*)((char*)d_ws + xb_bytes);
    cvt_x<<<2048, 256, 0, stream>>>(X, (uint2*)Xbf, M_DIM * K_DIM / 4);
    cvt_w<<<2048, 256, 0, stream>>>(W, S, (uint2*)Wbf, N_DIM * K_DIM / 4);
    static int attr_set = 0;
    if (!attr_set) {
      hipFuncSetAttribute((const void*)gemm_ring,
                          hipFuncAttributeMaxDynamicSharedMemorySize, 131072);
      attr_set = 1;
    }
    dim3 grid((M_DIM / 256) * (N_DIM / 256));  // 32 * 24 = 768
    gemm_ring<<<grid, 512, 131072, stream>>>(Xbf, Wbf, Y);
  } else {
    dim3 grid((M_DIM / BM) * (N_DIM / BN));
    dq_gemm<<<grid, 256, 0, stream>>>(X, W, S, Y);
  }
}

// Round 7
// 320.940 us; speedup vs baseline: 1.1522x; 1.0223x over previous
//
#include <hip/hip_runtime.h>

#define M_DIM 8192
#define N_DIM 6144
#define K_DIM 3072
#define NBK (K_DIM / 128) // 24 scale blocks along K

typedef __attribute__((ext_vector_type(8))) short short8;
typedef __attribute__((ext_vector_type(4))) float f32x4v;

// round-to-nearest-even f32->bf16, two packed into a u32
__device__ __forceinline__ unsigned int pk2bf(float a, float b) {
  unsigned int ua = __float_as_uint(a);
  unsigned int ub = __float_as_uint(b);
  ua = (ua + 0x7FFFu + ((ua >> 16) & 1u)) >> 16;
  ub = (ub + 0x7FFFu + ((ub >> 16) & 1u)) & 0xFFFF0000u;
  return ua | ub;
}

__global__ void cvt_x(const float* __restrict__ X, uint2* __restrict__ O, int n4) {
  int stride = gridDim.x * blockDim.x;
  for (int i = blockIdx.x * blockDim.x + threadIdx.x; i < n4; i += stride) {
    float4 v = ((const float4*)X)[i];
    O[i] = make_uint2(pk2bf(v.x, v.y), pk2bf(v.z, v.w));
  }
}

__global__ void cvt_w(const float* __restrict__ W, const float* __restrict__ S,
                      uint2* __restrict__ O, int n4) {
  int stride = gridDim.x * blockDim.x;
  for (int i = blockIdx.x * blockDim.x + threadIdx.x; i < n4; i += stride) {
    unsigned int e = (unsigned int)i * 4u;
    unsigned int n = e / K_DIM;
    unsigned int k = e - n * K_DIM;
    float s = S[(n >> 7) * NBK + (k >> 7)];
    float4 v = ((const float4*)W)[i];
    O[i] = make_uint2(pk2bf(v.x * s, v.y * s), pk2bf(v.z * s, v.w * s));
  }
}

__device__ __forceinline__ void gload16(const unsigned short* g, char* l) {
  __builtin_amdgcn_global_load_lds(
      (const __attribute__((address_space(1))) void*)g,
      (__attribute__((address_space(3))) void*)l, 16, 0, 0);
}

// 256x256 tile, BK=64, 8-phase schedule (m201-style) on parity double-buffer.
// K_DIM/64 = 48 K-tiles total: prologue stages kt0,kt1; 23 main iterations
// (kt=0..45, staging kt+2 <= 47); drain tiles kt=46 (vmcnt0) and kt=47.
// LDS: A[p][h] 4x16KB @0, B[p][h] 4x16KB @64KB (p = K-tile parity, h = half).
// Row = 128B (8 x 16B chunks), chunk swizzle: stored chunk = c ^ (row&7).
// Per K-tile, 4 phases = C-quadrants (0,0),(0,1),(1,1),(1,0):
//   ph0: rd A(qr0) 8 + B(qc0) 4           | mfma quad(0,0)
//   ph1: rd B(qc1) 4                       | mfma quad(0,1)
//   ph2: rd A(qr1) 8 | stage B(kt+2)       | mfma quad(1,1)
//   ph3: stage A(kt+2) | mfma quad(1,0)    | vmcnt(8) tail
// Each phase: {rd/stage, barrier, lgkmcnt(0), setprio1, 16 MFMA, setprio0, barrier}.
// Race-free: B[p] reads complete before ph1's closing barrier (stage at ph2);
// A[p] reads complete before ph2's closing barrier (stage at ph3).
__global__ __launch_bounds__(512, 2) void gemm_8ph(
    const unsigned short* __restrict__ Xb, const unsigned short* __restrict__ Wb,
    float* __restrict__ Y) {
  extern __shared__ char lds[];   // 128 KB

  int bid = blockIdx.x;
  int c = bid & 7;
  int j = bid >> 3;                 // 0..95
  int bm = c * 4 + (j / 24);        // 0..31
  int bn = j % 24;                  // 0..23

  int tid = threadIdx.x;
  int lane = tid & 63;
  int wid = tid >> 6;
  int wr = wid >> 2;                // 0..1
  int wc = wid & 3;                 // 0..3

  // staging: thread t covers row (t>>3) (+64/+128/+192), swizzled chunk in-line
  int srow = tid >> 3;                          // 0..63
  int sc = (tid & 7) ^ (srow & 7);              // source chunk (128B line local)
  const unsigned short* gx = Xb + ((size_t)bm * 256 + srow) * K_DIM + sc * 8;
  const unsigned short* gw = Wb + ((size_t)bn * 256 + srow) * K_DIM + sc * 8;
  char* ldsA = lds;                 // A(p) @ p*32768 (256 rows x 128B)
  char* ldsB = lds + 65536;         // B(p) @ p*32768

#define STAGE_A(P, KT2) {                                                        \
    const unsigned short* _g = gx + (size_t)(KT2) * 64;                          \
    char* _d = ldsA + (P) * 32768 + tid * 16;                                    \
    gload16(_g,                        _d);                                      \
    gload16(_g + (size_t) 64 * K_DIM,  _d + 8192);                               \
    gload16(_g + (size_t)128 * K_DIM,  _d + 16384);                              \
    gload16(_g + (size_t)192 * K_DIM,  _d + 24576); }
#define STAGE_B(P, KT2) {                                                        \
    const unsigned short* _g = gw + (size_t)(KT2) * 64;                          \
    char* _d = ldsB + (P) * 32768 + tid * 16;                                    \
    gload16(_g,                        _d);                                      \
    gload16(_g + (size_t) 64 * K_DIM,  _d + 8192);                               \
    gload16(_g + (size_t)128 * K_DIM,  _d + 16384);                              \
    gload16(_g + (size_t)192 * K_DIM,  _d + 24576); }

  // fragment read bases (byte offsets; row=128B, chunk swizzled by lane&7)
  int fr = lane & 15;
  int cq = (lane >> 4) ^ (lane & 7);            // ks=0 chunk slot
  const char* aB0 = ldsA + wr * 16384 + fr * 128 + (cq << 4);
  const char* aB1 = ldsA + wr * 16384 + fr * 128 + ((cq ^ 4) << 4);
  const char* bB0 = ldsB + wc * 8192 + fr * 128 + (cq << 4);
  const char* bB1 = ldsB + wc * 8192 + fr * 128 + ((cq ^ 4) << 4);

  f32x4v acc[8][4];
#pragma unroll
  for (int m = 0; m < 8; ++m)
#pragma unroll
    for (int n = 0; n < 4; ++n) acc[m][n] = (f32x4v)0.0f;

#define RD_A(P, QR) { _Pragma("unroll") for (int m = 0; m < 4; ++m) {            \
      ak0[m] = *(const short8*)(aB0 + (P) * 32768 + (QR) * 8192 + m * 2048);     \
      ak1[m] = *(const short8*)(aB1 + (P) * 32768 + (QR) * 8192 + m * 2048); } }
#define RD_B(P, QC, D0, D1) { _Pragma("unroll") for (int n = 0; n < 2; ++n) {    \
      D0[n] = *(const short8*)(bB0 + (P) * 32768 + (QC) * 4096 + n * 2048);      \
      D1[n] = *(const short8*)(bB1 + (P) * 32768 + (QC) * 4096 + n * 2048); } }
#define MM(QR, QC, B0_, B1_) { _Pragma("unroll") for (int m = 0; m < 4; ++m)     \
    _Pragma("unroll") for (int n = 0; n < 2; ++n) {                              \
      acc[(QR)*4+m][(QC)*2+n] = __builtin_amdgcn_mfma_f32_16x16x32_bf16(         \
          ak0[m], B0_[n], acc[(QR)*4+m][(QC)*2+n], 0, 0, 0);                     \
      acc[(QR)*4+m][(QC)*2+n] = __builtin_amdgcn_mfma_f32_16x16x32_bf16(         \
          ak1[m], B1_[n], acc[(QR)*4+m][(QC)*2+n], 0, 0, 0); } }
#define PH_SYNC asm volatile("s_barrier" ::: "memory");                          \
    asm volatile("s_waitcnt lgkmcnt(0)" ::: "memory");                           \
    __builtin_amdgcn_sched_barrier(0);
#define PH_END  asm volatile("s_barrier" ::: "memory");

  // VMTAIL codes: 2 -> vmcnt(8), 1 -> vmcnt(0), 0 -> none  (before closing barrier)
#define TILE(P, KT, DOSTAGE, VMT) {                                              \
    short8 ak0[4], ak1[4], bq0k0[2], bq0k1[2], bq1k0[2], bq1k1[2];               \
    /* ph0 */ RD_A(P, 0); RD_B(P, 0, bq0k0, bq0k1);                              \
    PH_SYNC; __builtin_amdgcn_s_setprio(1); MM(0, 0, bq0k0, bq0k1);              \
    __builtin_amdgcn_s_setprio(0); PH_END;                                       \
    /* ph1 */ RD_B(P, 1, bq1k0, bq1k1);                                          \
    PH_SYNC; __builtin_amdgcn_s_setprio(1); MM(0, 1, bq1k0, bq1k1);              \
    __builtin_amdgcn_s_setprio(0); PH_END;                                       \
    /* ph2 */ RD_A(P, 1); if (DOSTAGE) STAGE_B(P, (KT) + 2);                     \
    PH_SYNC; __builtin_amdgcn_s_setprio(1); MM(1, 1, bq1k0, bq1k1);              \
    __builtin_amdgcn_s_setprio(0); PH_END;                                       \
    /* ph3 */ if (DOSTAGE) STAGE_A(P, (KT) + 2);                                 \
    PH_SYNC; __builtin_amdgcn_s_setprio(1); MM(1, 0, bq0k0, bq0k1);              \
    __builtin_amdgcn_s_setprio(0);                                               \
    if (VMT == 2) { asm volatile("s_waitcnt vmcnt(8)" ::: "memory"); }           \
    else if (VMT == 1) { asm volatile("s_waitcnt vmcnt(0)" ::: "memory"); }      \
    PH_END; }

  // prologue: stage kt=0 (p0) and kt=1 (p1); wait kt0's 8, barrier
  STAGE_A(0, 0); STAGE_B(0, 0);
  STAGE_A(1, 1); STAGE_B(1, 1);
  asm volatile("s_waitcnt vmcnt(8)\n\ts_barrier" ::: "memory");

  for (int it = 0; it < 23; ++it) {   // kt = 0..45, staging kt+2 = 2..47
    int kt = it * 2;
    TILE(0, kt, 1, 2);
    TILE(1, kt + 1, 1, 2);
  }
  TILE(0, 46, 0, 1);   // drain kt47's loads
  TILE(1, 47, 0, 0);
#undef TILE
#undef PH_SYNC
#undef PH_END
#undef MM
#undef RD_A
#undef RD_B
#undef STAGE_A
#undef STAGE_B

  // C/D layout: ncol = lane&15, mrow = (lane>>4)*4 + reg
  int mrow0 = bm * 256 + wr * 128 + ((lane >> 4) << 2);
  int ncol0 = bn * 256 + wc * 64 + (lane & 15);
#pragma unroll
  for (int m = 0; m < 8; ++m)
#pragma unroll
    for (int n = 0; n < 4; ++n)
#pragma unroll
      for (int r = 0; r < 4; ++r)
        Y[(size_t)(mrow0 + m * 16 + r) * N_DIM + ncol0 + n * 16] = acc[m][n][r];
}

// ================= fallback (R1 kernel) if ws too small =================
#define BM 128
#define BN 128
#define NTN (N_DIM / BN)
#define NK2 (K_DIM / 64)
__global__ __launch_bounds__(256, 2) void dq_gemm(
    const float* __restrict__ X, const float* __restrict__ W,
    const float* __restrict__ S, float* __restrict__ Y) {
  __shared__ unsigned short As[BM * 64];
  __shared__ unsigned short Bs[BN * 64];
  int bid = blockIdx.x;
  int cpx = gridDim.x >> 3;
  int wg = (bid & 7) * cpx + (bid >> 3);
  int bm = wg / NTN, bn = wg - (wg / NTN) * NTN;
  int tid = threadIdx.x, lane = tid & 63, wave = tid >> 6;
  int wm = (wave >> 1) << 6, wn = (wave & 1) << 6;
  const float* Xg = X + (size_t)bm * BM * K_DIM;
  const float* Wg = W + (size_t)bn * BN * K_DIM;
  int r0 = tid >> 4, c4 = tid & 15;
  f32x4v acc[4][4];
#pragma unroll
  for (int i = 0; i < 4; ++i)
#pragma unroll
    for (int jj = 0; jj < 4; ++jj) acc[i][jj] = (f32x4v)0.0f;
  float4 xa[8], xb[8];
#pragma unroll
  for (int i = 0; i < 8; ++i) xa[i] = *(const float4*)(Xg + (size_t)(i * 16 + r0) * K_DIM + c4 * 4);
#pragma unroll
  for (int i = 0; i < 8; ++i) xb[i] = *(const float4*)(Wg + (size_t)(i * 16 + r0) * K_DIM + c4 * 4);
  char* Ac = (char*)As; char* Bc = (char*)Bs;
  int sw = (lane & 7) << 4, kb = (lane >> 4) << 4;
  int rA = wm + (lane & 15), rB = wn + (lane & 15);
  for (int kk = 0; kk < NK2; ++kk) {
    float s = S[bn * NBK + (kk >> 1)];
    __syncthreads();
#pragma unroll
    for (int i = 0; i < 8; ++i) {
      int row = i * 16 + r0;
      int off = row * 128 + ((c4 * 8) ^ ((row & 7) << 4));
      *(uint2*)(Ac + off) = make_uint2(pk2bf(xa[i].x, xa[i].y), pk2bf(xa[i].z, xa[i].w));
      *(uint2*)(Bc + off) = make_uint2(pk2bf(xb[i].x * s, xb[i].y * s), pk2bf(xb[i].z * s, xb[i].w * s));
    }
    __syncthreads();
    if (kk + 1 < NK2) {
      const float* Xn = Xg + (size_t)(kk + 1) * 64;
      const float* Wn = Wg + (size_t)(kk + 1) * 64;
#pragma unroll
      for (int i = 0; i < 8; ++i) xa[i] = *(const float4*)(Xn + (size_t)(i * 16 + r0) * K_DIM + c4 * 4);
#pragma unroll
      for (int i = 0; i < 8; ++i) xb[i] = *(const float4*)(Wn + (size_t)(i * 16 + r0) * K_DIM + c4 * 4);
    }
    short8 a0[4], a1[4], b0[4], b1[4];
#pragma unroll
    for (int i = 0; i < 4; ++i) {
      int rowA = rA + i * 16, rowB = rB + i * 16;
      a0[i] = *(const short8*)(Ac + rowA * 128 + (kb ^ sw));
      a1[i] = *(const short8*)(Ac + rowA * 128 + ((kb + 64) ^ sw));
      b0[i] = *(const short8*)(Bc + rowB * 128 + (kb ^ sw));
      b1[i] = *(const short8*)(Bc + rowB * 128 + ((kb + 64) ^ sw));
    }
#pragma unroll
    for (int i = 0; i < 4; ++i)
#pragma unroll
      for (int jj = 0; jj < 4; ++jj) {
        acc[i][jj] = __builtin_amdgcn_mfma_f32_16x16x32_bf16(a0[i], b0[jj], acc[i][jj], 0, 0, 0);
        acc[i][jj] = __builtin_amdgcn_mfma_f32_16x16x32_bf16(a1[i], b1[jj], acc[i][jj], 0, 0, 0);
      }
  }
  int mrow0 = bm * BM + wm + ((lane >> 4) << 2);
  int ncol0 = bn * BN + wn + (lane & 15);
#pragma unroll
  for (int i = 0; i < 4; ++i)
#pragma unroll
    for (int jj = 0; jj < 4; ++jj)
#pragma unroll
      for (int r = 0; r < 4; ++r)
        Y[(size_t)(mrow0 + i * 16 + r) * N_DIM + ncol0 + jj * 16] = acc[i][jj][r];
}

extern "C" void kernel_launch(void* const* d_in, const int* in_sizes, int n_in,
                              void* d_out, int out_size, void* d_ws, size_t ws_size,
                              hipStream_t stream) {
  const float* X = (const float*)d_in[0];
  const float* W = (const float*)d_in[1];
  const float* S = (const float*)d_in[2];
  float* Y = (float*)d_out;

  const size_t xb_bytes = (size_t)M_DIM * K_DIM * 2;
  const size_t wb_bytes = (size_t)N_DIM * K_DIM * 2;
  if (ws_size >= xb_bytes + wb_bytes) {
    unsigned short* Xbf = (unsigned short*)d_ws;
    unsigned short* Wbf = (unsigned short*)((char*)d_ws + xb_bytes);
    cvt_x<<<2048, 256, 0, stream>>>(X, (uint2*)Xbf, M_DIM * K_DIM / 4);
    cvt_w<<<2048, 256, 0, stream>>>(W, S, (uint2*)Wbf, N_DIM * K_DIM / 4);
    static int attr_set = 0;
    if (!attr_set) {
      hipFuncSetAttribute((const void*)gemm_8ph,
                          hipFuncAttributeMaxDynamicSharedMemorySize, 131072);
      attr_set = 1;
    }
    dim3 grid((M_DIM / 256) * (N_DIM / 256));  // 768
    gemm_8ph<<<grid, 512, 131072, stream>>>(Xbf, Wbf, Y);
  } else {
    dim3 grid((M_DIM / BM) * (N_DIM / BN));
    dq_gemm<<<grid, 256, 0, stream>>>(X, W, S, Y);
  }
}